// Round 7
// baseline (68.286 us; speedup 1.0000x reference)
//
#include <hip/hip_runtime.h>

#define NPIX 9216          // C*H*W = 1*96*96
#define NROWS (NPIX + 1)   // 9217 rows in zonotope
#define ROW4 (NPIX / 4)    // 2304 f32x4 per row
#define EPSV 0.1f

#define FILL_BLOCKS 2592   // 2592 * 256 * 32 = 21,233,664 f32x4 = rows 1..9216
#define ITERS 32
#define CHUNK4 (256 * ITERS)        // f32x4 per block chunk
#define CHUNKF (CHUNK4 * 4)         // floats per block chunk

typedef float f32x4 __attribute__((ext_vector_type(4)));

// ---------------------------------------------------------------------------
// Single kernel. Blocks 0..2591: zero a contiguous 128 KB chunk of rows
// 1..9216, redundantly compute the full stream-compaction scan from x
// (36 KB, L2-resident), then overwrite the <=5 nonzero cells that fall in
// this block's chunk. Block 2592: bias row 0. The __syncthreads between the
// zero-fill and the overwrite drains vmcnt for all waves, ordering the two
// stores to the same address.
// ---------------------------------------------------------------------------
__global__ __launch_bounds__(256) void zono_kernel(const float* __restrict__ x,
                                                   float* __restrict__ out) {
    const int b   = blockIdx.x;
    const int tid = threadIdx.x;
    f32x4* out4 = reinterpret_cast<f32x4*>(out);
    const f32x4* x4 = reinterpret_cast<const f32x4*>(x);

    if (b == FILL_BLOCKS) {
        // bias row (row 0): out[0][c] = clipped zonotope center
#pragma unroll
        for (int it = 0; it < 9; ++it) {
            const int c4 = tid + it * 256;
            const f32x4 xv = x4[c4];
            f32x4 o;
#pragma unroll
            for (int d = 0; d < 4; ++d) {
                const float v = xv[d];
                o[d] = v + fmaxf(EPSV - v, 0.0f) * 0.5f
                         - fmaxf(v - (1.0f - EPSV), 0.0f) * 0.5f;
            }
            out4[c4] = o;
        }
        return;
    }

    // ---- phase 1: zero my contiguous chunk (store stream = the bottleneck)
    {
        const f32x4 z = {0.0f, 0.0f, 0.0f, 0.0f};
        f32x4* p = out4 + ROW4 + b * CHUNK4 + tid;
#pragma unroll
        for (int it = 0; it < ITERS; ++it) {
            p[0] = z;
            p += 256;
        }
    }

    // ---- phase 2: full compaction scan (thread owns pixels [tid*36, tid*36+36))
    f32x4 e_loc[9];
    int cnt = 0;
#pragma unroll
    for (int i = 0; i < 9; ++i) {
        const f32x4 xv = x4[tid * 9 + i];
        f32x4 ev;
#pragma unroll
        for (int d = 0; d < 4; ++d) {
            const float v  = xv[d];
            const float rl = fmaxf(EPSV - v, 0.0f) * 0.5f;
            const float rh = fmaxf(v - (1.0f - EPSV), 0.0f) * 0.5f;
            ev[d] = EPSV - rl - rh;
            cnt += (ev[d] >= 0.0f) ? 1 : 0;
        }
        e_loc[i] = ev;
    }

    const int lane = tid & 63;
    const int wid  = tid >> 6;
    __shared__ int wsum[4];

    int v = cnt;
#pragma unroll
    for (int off = 1; off < 64; off <<= 1) {
        const int t = __shfl_up(v, off, 64);
        if (lane >= off) v += t;
    }
    if (lane == 63) wsum[wid] = v;
    __syncthreads();   // scan exchange + orders phase-1 zeros before phase-3

    int woff = 0;
#pragma unroll
    for (int w = 0; w < 4; ++w) woff += (w < wid) ? wsum[w] : 0;

    // ---- phase 3: overwrite the nonzero cells that land in my chunk
    int slot = woff + v - cnt;                    // exclusive prefix (0-based)
    const int floatLo = NPIX + b * CHUNKF;        // chunk start, float units
    const int floatHi = floatLo + CHUNKF;
    const int pbase = tid * 36;
#pragma unroll
    for (int i = 0; i < 9; ++i) {
#pragma unroll
        for (int d = 0; d < 4; ++d) {
            const float e = e_loc[i][d];
            if (e >= 0.0f) {
                ++slot;                           // 1-based slot == output row
                const int c = slot * NPIX + (pbase + i * 4 + d);
                if (c >= floatLo && c < floatHi) out[c] = e;
            }
        }
    }
}

extern "C" void kernel_launch(void* const* d_in, const int* in_sizes, int n_in,
                              void* d_out, int out_size, void* d_ws, size_t ws_size,
                              hipStream_t stream) {
    const float* x = (const float*)d_in[0];
    float* out = (float*)d_out;

    zono_kernel<<<FILL_BLOCKS + 1, 256, 0, stream>>>(x, out);
}

// Round 8
// 62.609 us; speedup vs baseline: 1.0907x; 1.0907x over previous
//
#include <hip/hip_runtime.h>

#define NPIX 9216          // C*H*W = 1*96*96
#define NROWS (NPIX + 1)   // 9217 rows in zonotope
#define ROW4 (NPIX / 4)    // 2304 f32x4 per row
#define EPSV 0.1f

typedef float f32x4 __attribute__((ext_vector_type(4)));

// ---------------------------------------------------------------------------
// Runs after hipMemsetAsync(d_out, 0) in stream order. Single block, 1024
// threads:
//  - row 0 = clipped bias (overwrites the memset zeros; coalesced f32x4)
//  - per-pixel err + cond, block-wide shuffle scan (stream compaction)
//  - scatter: out[slot*NPIX + pixel] = err  (~3.7K dword stores)
// Rows past the compacted count keep the memset zeros.
// ---------------------------------------------------------------------------
__global__ __launch_bounds__(1024) void finish_kernel(const float* __restrict__ x,
                                                      float* __restrict__ out) {
    __shared__ int wsum[16];
    const int tid  = threadIdx.x;
    const int lane = tid & 63;
    const int wid  = tid >> 6;
    const int base = tid * 9;      // 9 contiguous pixels per thread

    float e_loc[9];
    int   c_loc[9];
    int   cnt = 0;
#pragma unroll
    for (int k = 0; k < 9; ++k) {
        const float xv     = x[base + k];
        const float r_low  = fmaxf(EPSV - xv, 0.0f) * 0.5f;
        const float r_high = fmaxf(xv - (1.0f - EPSV), 0.0f) * 0.5f;
        const float e      = EPSV - r_low - r_high;
        e_loc[k] = e;
        c_loc[k] = (e >= 0.0f) ? 1 : 0;
        cnt += c_loc[k];
    }

    // inclusive shuffle scan of per-thread counts within each wave
    int v = cnt;
#pragma unroll
    for (int off = 1; off < 64; off <<= 1) {
        const int t = __shfl_up(v, off, 64);
        if (lane >= off) v += t;
    }
    if (lane == 63) wsum[wid] = v;
    __syncthreads();

    int woff = 0;
#pragma unroll
    for (int w = 0; w < 16; ++w) woff += (w < wid) ? wsum[w] : 0;

    int slot = woff + v - cnt;     // exclusive prefix (0-based)
#pragma unroll
    for (int k = 0; k < 9; ++k) {
        if (c_loc[k]) {
            ++slot;                // 1-based compacted slot == output row
            out[(long long)slot * NPIX + (base + k)] = e_loc[k];
        }
    }

    // row 0: clipped bias, coalesced f32x4
    const f32x4* x4 = reinterpret_cast<const f32x4*>(x);
    f32x4* o4 = reinterpret_cast<f32x4*>(out);
#pragma unroll
    for (int it = 0; it < 3; ++it) {
        const int c4 = tid + it * 1024;
        if (c4 < ROW4) {
            const f32x4 xv = x4[c4];
            f32x4 o;
#pragma unroll
            for (int d = 0; d < 4; ++d) {
                const float vv = xv[d];
                o[d] = vv + fmaxf(EPSV - vv, 0.0f) * 0.5f
                          - fmaxf(vv - (1.0f - EPSV), 0.0f) * 0.5f;
            }
            o4[c4] = o;
        }
    }
}

extern "C" void kernel_launch(void* const* d_in, const int* in_sizes, int n_in,
                              void* d_out, int out_size, void* d_ws, size_t ws_size,
                              hipStream_t stream) {
    const float* x = (const float*)d_in[0];
    float* out = (float*)d_out;

    // Bulk zero via the runtime's tuned fill kernel (graph-captures as a
    // memset node; measured at 6.8-7.1 TB/s on this chip vs ~5.5 for our
    // hand-rolled fill). Covers all rows incl. row 0; finish_kernel then
    // overwrites row 0 and scatters the nonzeros in stream order.
    hipMemsetAsync(d_out, 0, (size_t)out_size * sizeof(float), stream);
    finish_kernel<<<1, 1024, 0, stream>>>(x, out);
}

// Round 9
// 60.525 us; speedup vs baseline: 1.1282x; 1.0344x over previous
//
#include <hip/hip_runtime.h>

#define NPIX 9216          // C*H*W = 1*96*96
#define NROWS (NPIX + 1)   // 9217 rows in zonotope
#define ROW4 (NPIX / 4)    // 2304 f32x4 per row
#define BLKS_PER_ROW 9     // 2304 / 256
#define EPSV 0.1f

typedef float f32x4 __attribute__((ext_vector_type(4)));

// ---------------------------------------------------------------------------
// Kernel 1: stream compaction. Per-row descriptor iv[row] = {pixel, bits(err)}
// for rows 1..K (1-based compacted slots), {-1, 0} elsewhere (incl. row 0).
// Single block, 1024 threads; NPIX = 1024 * 9 exactly.
// ---------------------------------------------------------------------------
__global__ __launch_bounds__(1024) void prep_kernel(const float* __restrict__ x,
                                                    int2* __restrict__ iv) {
    __shared__ int wsum[16];
    const int tid  = threadIdx.x;
    const int lane = tid & 63;
    const int wid  = tid >> 6;
    const int base = tid * 9;

    for (int s = tid; s < NROWS; s += 1024) iv[s] = make_int2(-1, 0);

    float e_loc[9];
    int   c_loc[9];
    int   cnt = 0;
#pragma unroll
    for (int k = 0; k < 9; ++k) {
        const float xv     = x[base + k];
        const float r_low  = fmaxf(EPSV - xv, 0.0f) * 0.5f;
        const float r_high = fmaxf(xv - (1.0f - EPSV), 0.0f) * 0.5f;
        const float e      = EPSV - r_low - r_high;
        e_loc[k] = e;
        c_loc[k] = (e >= 0.0f) ? 1 : 0;
        cnt += c_loc[k];
    }

    // inclusive shuffle scan of per-thread counts within each wave
    int v = cnt;
#pragma unroll
    for (int off = 1; off < 64; off <<= 1) {
        const int t = __shfl_up(v, off, 64);
        if (lane >= off) v += t;
    }
    if (lane == 63) wsum[wid] = v;
    __syncthreads();   // also orders the -1 init before the scatter below

    int woff = 0;
#pragma unroll
    for (int w = 0; w < 16; ++w) woff += (w < wid) ? wsum[w] : 0;

    int slot = woff + v - cnt;     // exclusive prefix (0-based)
#pragma unroll
    for (int k = 0; k < 9; ++k) {
        if (c_loc[k]) {
            ++slot;                // 1-based compacted slot == output row
            iv[slot] = make_int2(base + k, __float_as_int(e_loc[k]));
        }
    }
}

// ---------------------------------------------------------------------------
// Kernel 2: loop-free fused write. Exactly one f32x4 store per thread,
// 82,953 blocks x 256 threads covering all 9217 rows in a single linear
// sweep (fillBufferAligned-style: the in-flight write window is one
// contiguous region marching through HBM -> DRAM-page friendly).
//   row  = blockIdx.x / 9   (scalar)
//   col4 = (blockIdx.x % 9) * 256 + tid
// Row 0: bias from x. Row >= 1: zero except err at iv[row].x (block-uniform
// scalar load; -1 for unused rows never matches).
// ---------------------------------------------------------------------------
__global__ __launch_bounds__(256) void write_kernel(const float* __restrict__ x,
                                                    const int2* __restrict__ iv,
                                                    f32x4* __restrict__ out) {
    const int bid  = blockIdx.x;
    const int row  = bid / BLKS_PER_ROW;             // scalar magic-div
    const int sub  = bid - row * BLKS_PER_ROW;
    const int col4 = sub * 256 + threadIdx.x;

    f32x4 o;
    if (row == 0) {
        const f32x4 xv = reinterpret_cast<const f32x4*>(x)[col4];
#pragma unroll
        for (int d = 0; d < 4; ++d) {
            const float v = xv[d];
            o[d] = v + fmaxf(EPSV - v, 0.0f) * 0.5f
                     - fmaxf(v - (1.0f - EPSV), 0.0f) * 0.5f;
        }
    } else {
        const int2 p = iv[row];                      // block-uniform scalar load
        const float e = __int_as_float(p.y);
        const int col = col4 * 4;
        o.x = (p.x == col)     ? e : 0.0f;
        o.y = (p.x == col + 1) ? e : 0.0f;
        o.z = (p.x == col + 2) ? e : 0.0f;
        o.w = (p.x == col + 3) ? e : 0.0f;
    }
    out[(long long)row * ROW4 + col4] = o;
}

extern "C" void kernel_launch(void* const* d_in, const int* in_sizes, int n_in,
                              void* d_out, int out_size, void* d_ws, size_t ws_size,
                              hipStream_t stream) {
    const float* x = (const float*)d_in[0];
    float* out = (float*)d_out;
    int2* iv = (int2*)d_ws;       // NROWS descriptors

    prep_kernel<<<1, 1024, 0, stream>>>(x, iv);
    write_kernel<<<NROWS * BLKS_PER_ROW, 256, 0, stream>>>(x, iv, (f32x4*)out);
}